// Round 3
// baseline (881.379 us; speedup 1.0000x reference)
//
#include <hip/hip_runtime.h>

// DynamicFilterLayerOneChannel:
//   out[n,h,w] = sum_{ky,kx} x[n,h+ky-4,w+kx-4] * F[n,ky*9+kx,h,w] + b[n,h,w]
// Memory-bound on streaming F (~677 MB, read once). v2: each thread computes
// 8 consecutive w-pixels (two adjacent float4 groups per (dy,dx) plane):
//  - per-wave contiguous chunk per filter plane: 2 KB (was 1 KB) -> better
//    DRAM page locality; 2nd load shares the address reg (offset:16 fold).
//  - vector-mem + address-VALU instructions per byte ~halved.
// dy-loop kept rolled (#pragma unroll 1) to cap VGPR pressure (~120, no
// spill); launch_bounds(256,4) keeps 4 waves/EU. Grid 255x4 = 1020 blocks,
// ~4 blocks/CU co-resident, exact cover (65280 = 255*256 groups/batch).

#define KS   9
#define PADV 4
#define NN   4
#define HH   544
#define WW   960
#define W8   (WW / 8)          // 120
#define HW   (HH * WW)         // 522240

typedef float vf4 __attribute__((ext_vector_type(4)));

__global__ __launch_bounds__(256, 4) void dynfilter_kernel(
    const float* __restrict__ x,
    const float* __restrict__ filt,
    const float* __restrict__ bias,
    float* __restrict__ out)
{
    const int n = blockIdx.y;                       // wave-uniform batch
    const int p = blockIdx.x * 256 + threadIdx.x;   // pixel-group id, < 65280
    const int w8 = p % W8;
    const int h  = p / W8;
    const int w0 = w8 * 8;

    const float* __restrict__ xb = x + (size_t)n * HW;
    const float* __restrict__ fn = filt + (size_t)n * KS * KS * HW;
    const int off = h * WW + w0;                    // per-lane 32-bit offset

    const float* bp = bias + (size_t)n * HW + off;
    vf4 acc0 = *reinterpret_cast<const vf4*>(bp);
    vf4 acc1 = *reinterpret_cast<const vf4*>(bp + 4);

    // need x cols [w0-4, w0+11] and rows [h-4, h+4]
    const bool interior = (w0 >= PADV) && (w0 + 11 < WW) &&
                          (h >= PADV) && (h + PADV < HH);

    if (interior) {
        const float* xr = xb + (h - PADV) * WW + (w0 - PADV);
        const float* fp = fn + off;
        #pragma unroll 1
        for (int dy = 0; dy < KS; ++dy) {
            vf4 a = *reinterpret_cast<const vf4*>(xr);
            vf4 b = *reinterpret_cast<const vf4*>(xr + 4);
            vf4 c = *reinterpret_cast<const vf4*>(xr + 8);
            vf4 d = *reinterpret_cast<const vf4*>(xr + 12);
            float xrow[16] = {a.x, a.y, a.z, a.w,
                              b.x, b.y, b.z, b.w,
                              c.x, c.y, c.z, c.w,
                              d.x, d.y, d.z, d.w};
            #pragma unroll
            for (int dx = 0; dx < KS; ++dx) {
                const float* fq = fp + dx * HW;
                vf4 f0 = __builtin_nontemporal_load(
                    reinterpret_cast<const vf4*>(fq));
                vf4 f1 = __builtin_nontemporal_load(
                    reinterpret_cast<const vf4*>(fq + 4));
                acc0.x += f0.x * xrow[dx + 0];
                acc0.y += f0.y * xrow[dx + 1];
                acc0.z += f0.z * xrow[dx + 2];
                acc0.w += f0.w * xrow[dx + 3];
                acc1.x += f1.x * xrow[dx + 4];
                acc1.y += f1.y * xrow[dx + 5];
                acc1.z += f1.z * xrow[dx + 6];
                acc1.w += f1.w * xrow[dx + 7];
            }
            xr += WW;
            fp += KS * HW;
        }
    } else {
        const float* fp = fn + off;
        #pragma unroll 1
        for (int dy = 0; dy < KS; ++dy) {
            int row = h + dy - PADV;
            bool rok = (row >= 0) && (row < HH);
            float xrow[16];
            #pragma unroll
            for (int j = 0; j < 16; ++j) {
                int col = w0 - PADV + j;
                bool ok = rok && (col >= 0) && (col < WW);
                xrow[j] = ok ? xb[row * WW + col] : 0.0f;
            }
            #pragma unroll
            for (int dx = 0; dx < KS; ++dx) {
                const float* fq = fp + dx * HW;
                vf4 f0 = __builtin_nontemporal_load(
                    reinterpret_cast<const vf4*>(fq));
                vf4 f1 = __builtin_nontemporal_load(
                    reinterpret_cast<const vf4*>(fq + 4));
                acc0.x += f0.x * xrow[dx + 0];
                acc0.y += f0.y * xrow[dx + 1];
                acc0.z += f0.z * xrow[dx + 2];
                acc0.w += f0.w * xrow[dx + 3];
                acc1.x += f1.x * xrow[dx + 4];
                acc1.y += f1.y * xrow[dx + 5];
                acc1.z += f1.z * xrow[dx + 6];
                acc1.w += f1.w * xrow[dx + 7];
            }
            fp += KS * HW;
        }
    }

    float* op = out + (size_t)n * HW + off;
    __builtin_nontemporal_store(acc0, reinterpret_cast<vf4*>(op));
    __builtin_nontemporal_store(acc1, reinterpret_cast<vf4*>(op + 4));
}

extern "C" void kernel_launch(void* const* d_in, const int* in_sizes, int n_in,
                              void* d_out, int out_size, void* d_ws, size_t ws_size,
                              hipStream_t stream) {
    const float* x    = (const float*)d_in[0];  // [4,1,544,960]
    const float* filt = (const float*)d_in[1];  // [4,81,544,960]
    const float* bias = (const float*)d_in[2];  // [4,1,544,960]
    float* out        = (float*)d_out;          // [4,1,544,960]

    dim3 grid((HH * W8) / 256, NN);             // 255 x 4 blocks, exact cover
    dynfilter_kernel<<<grid, dim3(256), 0, stream>>>(x, filt, bias, out);
}

// Round 6
// 871.644 us; speedup vs baseline: 1.0112x; 1.0112x over previous
//
#include <hip/hip_runtime.h>

// DynamicFilterLayerOneChannel:
//   out[n,h,w] = sum_{ky,kx} x[n,h+ky-4,w+kx-4] * F[n,ky*9+kx,h,w] + b[n,h,w]
// Memory-bound on streaming F (~677 MB, read once). v3: identical to the
// 851.7us 4px baseline EXCEPT filter loads are normal (cached) loads, not
// __builtin_nontemporal_load. A/B probe: inferred kernel time is ~425us
// (1.65 TB/s) vs a 111us roofline floor; latency/issue math says this
// pattern should saturate HBM, so the unmeasured nt-load path is the prime
// suspect for a per-CU bandwidth cap. nt STORE on out is kept (write-once).
// dy-loop kept rolled (#pragma unroll 1) to cap VGPR pressure -> no spills;
// launch_bounds(256,4) caps VGPRs at 128 (4 waves/EU).

#define KS   9
#define PADV 4
#define NN   4
#define HH   544
#define WW   960
#define W4   (WW / 4)          // 240
#define HW   (HH * WW)         // 522240

typedef float vf4 __attribute__((ext_vector_type(4)));

__global__ __launch_bounds__(256, 4) void dynfilter_kernel(
    const float* __restrict__ x,
    const float* __restrict__ filt,
    const float* __restrict__ bias,
    float* __restrict__ out)
{
    const int n = blockIdx.y;                       // wave-uniform batch
    const int p = blockIdx.x * 256 + threadIdx.x;   // pixel-group id, < 130560
    const int w4 = p % W4;
    const int h  = p / W4;
    const int w0 = w4 * 4;

    const float* __restrict__ xb = x + (size_t)n * HW;
    const float* __restrict__ fn = filt + (size_t)n * KS * KS * HW;  // scalar base
    const int off = h * WW + w0;                    // per-lane 32-bit offset

    vf4 acc = *reinterpret_cast<const vf4*>(bias + (size_t)n * HW + off);

    const bool interior = (w0 >= PADV) && (w0 + 7 < WW) &&
                          (h >= PADV) && (h + PADV < HH);

    if (interior) {
        const float* xr = xb + (h - PADV) * WW + (w0 - PADV);
        const float* fp = fn + off;
        #pragma unroll 1
        for (int dy = 0; dy < KS; ++dy) {
            vf4 a = *reinterpret_cast<const vf4*>(xr);
            vf4 b = *reinterpret_cast<const vf4*>(xr + 4);
            vf4 c = *reinterpret_cast<const vf4*>(xr + 8);
            float xrow[12] = {a.x, a.y, a.z, a.w,
                              b.x, b.y, b.z, b.w,
                              c.x, c.y, c.z, c.w};
            #pragma unroll
            for (int dx = 0; dx < KS; ++dx) {
                vf4 f = *reinterpret_cast<const vf4*>(fp + (size_t)dx * HW);
                acc.x += f.x * xrow[dx + 0];
                acc.y += f.y * xrow[dx + 1];
                acc.z += f.z * xrow[dx + 2];
                acc.w += f.w * xrow[dx + 3];
            }
            xr += WW;
            fp += (size_t)KS * HW;
        }
    } else {
        const float* fp = fn + off;
        #pragma unroll 1
        for (int dy = 0; dy < KS; ++dy) {
            int row = h + dy - PADV;
            bool rok = (row >= 0) && (row < HH);
            float xrow[12];
            #pragma unroll
            for (int j = 0; j < 12; ++j) {
                int col = w0 - PADV + j;
                bool ok = rok && (col >= 0) && (col < WW);
                xrow[j] = ok ? xb[row * WW + col] : 0.0f;
            }
            #pragma unroll
            for (int dx = 0; dx < KS; ++dx) {
                vf4 f = *reinterpret_cast<const vf4*>(fp + (size_t)dx * HW);
                acc.x += f.x * xrow[dx + 0];
                acc.y += f.y * xrow[dx + 1];
                acc.z += f.z * xrow[dx + 2];
                acc.w += f.w * xrow[dx + 3];
            }
            fp += (size_t)KS * HW;
        }
    }

    __builtin_nontemporal_store(acc,
        reinterpret_cast<vf4*>(out + (size_t)n * HW + off));
}

extern "C" void kernel_launch(void* const* d_in, const int* in_sizes, int n_in,
                              void* d_out, int out_size, void* d_ws, size_t ws_size,
                              hipStream_t stream) {
    const float* x    = (const float*)d_in[0];  // [4,1,544,960]
    const float* filt = (const float*)d_in[1];  // [4,81,544,960]
    const float* bias = (const float*)d_in[2];  // [4,1,544,960]
    float* out        = (float*)d_out;          // [4,1,544,960]

    dim3 grid((HH * W4) / 256, NN);             // 510 x 4 blocks, exact cover
    dynfilter_kernel<<<grid, dim3(256), 0, stream>>>(x, filt, bias, out);
}